// Round 11
// baseline (236.318 us; speedup 1.0000x reference)
//
#include <hip/hip_runtime.h>
#include <hip/hip_bf16.h>

// Problem constants
#define BB 8
#define SS 2048
#define DD 256
#define HH 512
#define LL 3
#define NROWS (BB * SS)
#define PSIBLK 1024      // psi blocks in launch 1
#define WCBN 192         // Wc blocks in launch 1 (3 layers x 64)

typedef float floatx4 __attribute__((ext_vector_type(4)));

// ---------------------------------------------------------------------------
// A/mask row worker: A[b,i,j] = psi[b,i,:].psi[b,j,:] ; mask = (i==j).
// Dense float4 NON-TEMPORAL stores (bypass L2: nothing to write back at
// launch boundaries).
// ---------------------------------------------------------------------------
__device__ __forceinline__ void amask_row(const float* __restrict__ psi,
                                          float* __restrict__ A, float* __restrict__ M,
                                          int blk)
{
    int tid = threadIdx.x;
    int b = blk >> 11, i = blk & (SS - 1);
    float2 pi = *reinterpret_cast<const float2*>(psi + (size_t)blk * 2);
    #pragma unroll
    for (int c = 0; c < 2; ++c) {
        int j0 = c * 1024 + tid * 4;
        const float4* pr = reinterpret_cast<const float4*>(psi + ((size_t)b * SS + j0) * 2);
        float4 q0 = pr[0], q1 = pr[1];
        floatx4 o;
        o.x = pi.x * q0.x + pi.y * q0.y;
        o.y = pi.x * q0.z + pi.y * q0.w;
        o.z = pi.x * q1.x + pi.y * q1.y;
        o.w = pi.x * q1.z + pi.y * q1.w;
        size_t rb = (size_t)blk * SS + j0;
        __builtin_nontemporal_store(o, reinterpret_cast<floatx4*>(A + rb));
        floatx4 m;
        m.x = (i == j0    ) ? 1.f : 0.f;
        m.y = (i == j0 + 1) ? 1.f : 0.f;
        m.z = (i == j0 + 2) ? 1.f : 0.f;
        m.w = (i == j0 + 3) ? 1.f : 0.f;
        __builtin_nontemporal_store(m, reinterpret_cast<floatx4*>(M + rb));
    }
}

// ---------------------------------------------------------------------------
// Launch 1: blocks 0..1023  : per-block M in LDS -> psi (16 rows) + h0
//           blocks 1024..   : Wc = Wo@Wv, bc = Wo@bv + bo  (parked in A tail)
// ---------------------------------------------------------------------------
__global__ void psiM_kernel(const float* __restrict__ x,
                            const float* __restrict__ pw, const float* __restrict__ pb,
                            const float* __restrict__ pe, const float* __restrict__ hebb,
                            const float* __restrict__ ai_w, const float* __restrict__ ai_b,
                            const float* __restrict__ ao_w, const float* __restrict__ ao_b,
                            float* __restrict__ psi, float* __restrict__ h0,
                            float* __restrict__ Wc, float* __restrict__ bc)
{
    __shared__ __align__(16) float sB[8 * HH];   // 16 KB: Wc staging / M (520 floats)
    const int tid = threadIdx.x;
    const int bid = blockIdx.x;

    if (bid >= PSIBLK) {
        // ---- Wc blocks: Wc[l][j,k] = sum_m Wo[l][j,m] * Wv[l][m,k] ----
        int wcb = bid - PSIBLK;
        int l = wcb >> 6;                 // 0..2
        int j0 = (wcb & 63) * 8;          // 8 Wo rows per block
        const float* WoB = ao_w + (size_t)l * HH * HH;
        for (int idx = tid; idx < 8 * HH; idx += 256) {
            int r = idx >> 9, m = idx & 511;
            sB[idx] = WoB[(size_t)(j0 + r) * HH + m];
        }
        __syncthreads();
        const float* WvB = ai_w + ((size_t)l * 3 * HH + 2 * HH) * HH;
        int k0 = tid, k1 = tid + 256;
        float acc0[8] = {0,0,0,0,0,0,0,0};
        float acc1[8] = {0,0,0,0,0,0,0,0};
        for (int m = 0; m < HH; ++m) {
            float w0 = WvB[(size_t)m * HH + k0];
            float w1 = WvB[(size_t)m * HH + k1];
            #pragma unroll
            for (int r = 0; r < 8; ++r) {
                float wo = sB[r * HH + m];
                acc0[r] = fmaf(wo, w0, acc0[r]);
                acc1[r] = fmaf(wo, w1, acc1[r]);
            }
        }
        #pragma unroll
        for (int r = 0; r < 8; ++r) {
            Wc[((size_t)l * HH + j0 + r) * HH + k0] = acc0[r];
            Wc[((size_t)l * HH + j0 + r) * HH + k1] = acc1[r];
        }
        if (tid < 8) {
            const float* bvB = ai_b + l * 3 * HH + 2 * HH;
            float s = ao_b[l * HH + j0 + tid];
            for (int m = 0; m < HH; ++m) s += sB[tid * HH + m] * bvB[m];
            bc[l * HH + j0 + tid] = s;
        }
        return;
    }

    // ---- psi blocks: M in LDS, then 16 rows of psi ----
    {
        float a0 = 0.f, a1 = 0.f;
        for (int d = 0; d < DD; ++d) {
            float w = pw[d * DD + tid];       // wave-contiguous in k=tid
            a0 += w * pe[2 * d];
            a1 += w * pe[2 * d + 1];
        }
        sB[2 * tid] = a0;
        sB[2 * tid + 1] = a1;
        if (tid < 64) {
            float c0 = 0.f, c1 = 0.f;
            for (int d = tid; d < DD; d += 64) {
                c0 += pb[d] * pe[2 * d];
                c1 += pb[d] * pe[2 * d + 1];
            }
            #pragma unroll
            for (int dd = 32; dd; dd >>= 1) {
                c0 += __shfl_xor(c0, dd);
                c1 += __shfl_xor(c1, dd);
            }
            if (tid == 0) { sB[512] = c0; sB[513] = c1; }
        }
    }
    __syncthreads();

    int wave = tid >> 6, lane = tid & 63;
    const float4* sM4 = reinterpret_cast<const float4*>(sB);
    float4 mA = sM4[lane * 2];
    float4 mB = sM4[lane * 2 + 1];
    float c0 = sB[512], c1 = sB[513];
    int base = bid * 16 + wave * 4;
    #pragma unroll
    for (int it = 0; it < 4; ++it) {
        int rid = base + it;
        float4 v = *reinterpret_cast<const float4*>(x + (size_t)rid * DD + lane * 4);
        float a0 = v.x * mA.x + v.y * mA.z + v.z * mB.x + v.w * mB.z;
        float a1 = v.x * mA.y + v.y * mA.w + v.z * mB.y + v.w * mB.w;
        #pragma unroll
        for (int d = 32; d; d >>= 1) {
            a0 += __shfl_xor(a0, d);
            a1 += __shfl_xor(a1, d);
        }
        a0 += c0;
        a1 += c1;
        float n = sqrtf(a0 * a0 + a1 * a1);
        float scale = 1.f / (n + 1e-8f);
        float r = n * scale;
        #pragma unroll
        for (int i7 = 0; i7 < 7; ++i7) {
            float f = r / (r + 1e-8f);
            scale *= f;
            r *= f;
        }
        float px = a0 * scale, py = a1 * scale;
        if (lane == 0) {
            float2 pv;
            pv.x = px;
            pv.y = py;
            *reinterpret_cast<float2*>(psi + (size_t)rid * 2) = pv;
        }
        if ((rid & (SS - 1)) == SS - 1) {       // h0 for this batch
            int b = rid >> 11;
            for (int j = lane; j < HH; j += 64)
                h0[(size_t)b * HH + j] = px * hebb[2 * j] + py * hebb[2 * j + 1];
        }
    }
}

// ---------------------------------------------------------------------------
// Generic tiny-batch (B=8) GEMM: out[b,j] = R[b,j] + act( bias[j] + LN?(X)[b,:] . W[j,:] )
//   - optional LN on X (and optional second LN stage), staged in dynamic LDS
//   - optional LN on residual R (stats only; values read from global)
//   - act: 0 = none, 1 = silu
//   - G lanes (power of 2) cooperate per output j, shuffle-reduced.
//   - blocks with blockIdx.x >= mmBlocks moonlight as A/mask row writers.
// ---------------------------------------------------------------------------
__global__ void head_mm(const float* __restrict__ X, int K,
                        const float* __restrict__ xlnw, const float* __restrict__ xlnb,
                        const float* __restrict__ xln2w, const float* __restrict__ xln2b,
                        const float* __restrict__ W, const float* __restrict__ bias,
                        const float* __restrict__ res,
                        const float* __restrict__ reslnw, const float* __restrict__ reslnb,
                        float* __restrict__ out, int J, int G, int act,
                        const float* __restrict__ psi,
                        float* __restrict__ Ao, float* __restrict__ Mo,
                        int mmBlocks, int arow0)
{
    const int bid = blockIdx.x;
    if (bid >= mmBlocks) {
        int r = arow0 + (bid - mmBlocks);
        if (r < NROWS) amask_row(psi, Ao, Mo, r);
        return;
    }

    extern __shared__ float sX[];           // 8*K floats when LN is active
    __shared__ float s_m[8], s_r[8], s_rm[8], s_rr[8];
    const int tid = threadIdx.x;
    const int row = tid >> 5, lane = tid & 31;   // 32 lanes per batch-row for stats
    const bool doLN = (xlnw != nullptr);
    const bool doRLN = (res != nullptr) && (reslnw != nullptr);

    if (doLN) {
        float s = 0.f, ss = 0.f;
        for (int k = lane; k < K; k += 32) {
            float v = X[row * K + k];
            s += v; ss += v * v;
        }
        for (int d = 16; d; d >>= 1) { s += __shfl_down(s, d); ss += __shfl_down(ss, d); }
        if (lane == 0) {
            float m = s / K;
            s_m[row] = m;
            s_r[row] = rsqrtf(ss / K - m * m + 1e-5f);
        }
    }
    if (doRLN) {
        float s = 0.f, ss = 0.f;
        for (int k = lane; k < J; k += 32) {
            float v = res[row * J + k];
            s += v; ss += v * v;
        }
        for (int d = 16; d; d >>= 1) { s += __shfl_down(s, d); ss += __shfl_down(ss, d); }
        if (lane == 0) {
            float m = s / J;
            s_rm[row] = m;
            s_rr[row] = rsqrtf(ss / J - m * m + 1e-5f);
        }
    }
    __syncthreads();

    if (doLN) {
        for (int idx = tid; idx < 8 * K; idx += 256) {
            int b = idx / K, k = idx - b * K;
            sX[idx] = (X[idx] - s_m[b]) * s_r[b] * xlnw[k] + xlnb[k];
        }
        __syncthreads();
        if (xln2w) {   // second LN stage (LN(LN(x)))
            float s = 0.f, ss = 0.f;
            for (int k = lane; k < K; k += 32) {
                float v = sX[row * K + k];
                s += v; ss += v * v;
            }
            for (int d = 16; d; d >>= 1) { s += __shfl_down(s, d); ss += __shfl_down(ss, d); }
            if (lane == 0) {
                float m = s / K;
                s_m[row] = m;
                s_r[row] = rsqrtf(ss / K - m * m + 1e-5f);
            }
            __syncthreads();
            for (int idx = tid; idx < 8 * K; idx += 256) {
                int b = idx / K, k = idx - b * K;
                sX[idx] = (sX[idx] - s_m[b]) * s_r[b] * xln2w[k] + xln2b[k];
            }
            __syncthreads();
        }
    }

    const float* __restrict__ Xp = doLN ? (const float*)sX : X;
    const int g = tid & (G - 1);
    const int jj = tid / G;
    const int j = bid * (256 / G) + jj;

    float acc[8] = {0.f, 0.f, 0.f, 0.f, 0.f, 0.f, 0.f, 0.f};
    if (j < J) {
        const float4* W4 = reinterpret_cast<const float4*>(W + (size_t)j * K);
        const int K4 = K >> 2;
        for (int i4 = g; i4 < K4; i4 += G) {
            float4 w4 = W4[i4];
            int k = i4 << 2;
            #pragma unroll
            for (int b = 0; b < 8; ++b) {
                float4 xv = *reinterpret_cast<const float4*>(Xp + b * K + k);
                acc[b] = fmaf(w4.x, xv.x, acc[b]);
                acc[b] = fmaf(w4.y, xv.y, acc[b]);
                acc[b] = fmaf(w4.z, xv.z, acc[b]);
                acc[b] = fmaf(w4.w, xv.w, acc[b]);
            }
        }
    }
    for (int d = G >> 1; d; d >>= 1) {
        #pragma unroll
        for (int b = 0; b < 8; ++b) acc[b] += __shfl_down(acc[b], d);
    }
    if (g == 0 && j < J) {
        float bs = bias ? bias[j] : 0.f;
        #pragma unroll
        for (int b = 0; b < 8; ++b) {
            float v = acc[b] + bs;
            if (act) v = v / (1.f + expf(-v));   // silu
            if (res) {
                float rv = res[(size_t)b * J + j];
                if (reslnw) rv = (rv - s_rm[b]) * s_rr[b] * reslnw[j] + reslnb[j];
                v += rv;
            }
            out[(size_t)b * J + j] = v;
        }
    }
}

// ---------------------------------------------------------------------------
extern "C" void kernel_launch(void* const* d_in, const int* in_sizes, int n_in,
                              void* d_out, int out_size, void* d_ws, size_t ws_size,
                              hipStream_t stream)
{
    const float* x      = (const float*)d_in[0];
    const float* proj_w = (const float*)d_in[1];
    const float* proj_b = (const float*)d_in[2];
    const float* pe     = (const float*)d_in[3];
    const float* hebb   = (const float*)d_in[4];
    const float* ai_w   = (const float*)d_in[5];
    const float* ai_b   = (const float*)d_in[6];
    const float* ao_w   = (const float*)d_in[7];
    const float* ao_b   = (const float*)d_in[8];
    const float* f1_w   = (const float*)d_in[9];
    const float* f1_b   = (const float*)d_in[10];
    const float* f2_w   = (const float*)d_in[11];
    const float* f2_b   = (const float*)d_in[12];
    const float* ln1w   = (const float*)d_in[13];
    const float* ln1b   = (const float*)d_in[14];
    const float* ln2w   = (const float*)d_in[15];
    const float* ln2b   = (const float*)d_in[16];
    const float* nAw    = (const float*)d_in[17];
    const float* nAb    = (const float*)d_in[18];
    const float* nBw    = (const float*)d_in[19];
    const float* nBb    = (const float*)d_in[20];
    const float* p1w    = (const float*)d_in[21];
    const float* p1b    = (const float*)d_in[22];
    const float* p2w    = (const float*)d_in[23];
    const float* p2b    = (const float*)d_in[24];

    float* out   = (float*)d_out;
    // output layout: preds(8) | A(B*S*S) | mask(B*S*S) | psi(B*S*2)
    float* preds = out;
    float* A     = out + 8;
    float* Mask  = out + 8 + (size_t)BB * SS * SS;
    float* Psi   = out + 8 + (size_t)2 * BB * SS * SS;

    // Wc parked in A rows 15000+ : last Wc read is layer-2 vo (launch #8);
    // these A rows are overwritten by carrier #11 (rows 14900+) — later in
    // stream order, so safe.
    float* Wc = A + (size_t)15000 * SS;
    float* bc = Wc + 3 * HH * HH;

    float* ws = (float*)d_ws;
    float* T  = ws + 640;      // 8x512 pre-LN state (starts as h0)
    float* T1 = ws + 8832;     // 8x512
    float* F  = ws + 12928;    // 8x2048
    float* P  = ws + 29312;    // 8x256

    // ---- Launch 1: psi + h0 + Wc (1216 blocks) ----
    psiM_kernel<<<PSIBLK + WCBN, 256, 0, stream>>>(
        x, proj_w, proj_b, pe, hebb, ai_w, ai_b, ao_w, ao_b, Psi, T, Wc, bc);

    // ---- 11 carriers moonlight the 16384 A/mask rows (1490 each) ----
    int ci = 0, arow = 0;
    auto nextq = [&]() { int q = (ci < 10) ? 1490 : (NROWS - 1490 * 10); ++ci; return q; };

    for (int l = 0; l < LL; ++l) {
        const float* pxw = l ? ln2w + (l - 1) * HH : nullptr;
        const float* pxb = l ? ln2b + (l - 1) * HH : nullptr;
        int q;
        // t1 = LN?(T) + LN?(T) @ Wc^T + bc    (fused v+o; J=512, K=512, G=32)
        q = nextq();
        head_mm<<<64 + q, 256, (pxw ? 8 * HH * 4 : 0), stream>>>(
            T, HH, pxw, pxb, nullptr, nullptr,
            Wc + (size_t)l * HH * HH, bc + l * HH,
            T, pxw, pxb, T1, HH, 32, 0,
            Psi, A, Mask, 64, arow);
        arow += q;
        // f = silu(LN(t1,ln1) @ W1^T + b1)    (J=2048, K=512, G=16)
        q = nextq();
        head_mm<<<128 + q, 256, 8 * HH * 4, stream>>>(
            T1, HH, ln1w + l * HH, ln1b + l * HH, nullptr, nullptr,
            f1_w + (size_t)l * 4 * HH * HH, f1_b + l * 4 * HH,
            nullptr, nullptr, nullptr, F, 4 * HH, 16, 1,
            Psi, A, Mask, 128, arow);
        arow += q;
        // t2 = LN(t1,ln1) + (f @ W2^T + b2)   (J=512, K=2048, G=64)
        q = nextq();
        head_mm<<<128 + q, 256, 0, stream>>>(
            F, 4 * HH, nullptr, nullptr, nullptr, nullptr,
            f2_w + (size_t)l * HH * 4 * HH, f2_b + l * HH,
            T1, ln1w + l * HH, ln1b + l * HH, T, HH, 64, 0,
            Psi, A, Mask, 128, arow);
        arow += q;
    }
    // p = silu( LN(LN(t2,ln2[2]),normA) @ p1^T + p1_b )   (J=256, K=512)
    {
        int q = nextq();
        head_mm<<<32 + q, 256, 8 * HH * 4, stream>>>(
            T, HH, ln2w + 2 * HH, ln2b + 2 * HH, nAw, nAb,
            p1w, p1b, nullptr, nullptr, nullptr, P, HH / 2, 32, 1,
            Psi, A, Mask, 32, arow);
        arow += q;
    }
    // preds = LN(p,normB) @ p2^T + p2_b                   (J=1, K=256)
    {
        int q = nextq();
        head_mm<<<1 + q, 256, 8 * (HH / 2) * 4, stream>>>(
            P, HH / 2, nBw, nBb, nullptr, nullptr,
            p2w, p2b, nullptr, nullptr, nullptr, preds, 1, 32, 0,
            Psi, A, Mask, 1, arow);
        arow += q;
    }
}